// Round 5
// baseline (21135.744 us; speedup 1.0000x reference)
//
#include <hip/hip_runtime.h>
#include <stdint.h>

#define SEQT   512
#define HID    512
#define GRPS   8      // batch groups (32 batches each)
#define SLICES 32     // h-slices per group (64 gate rows each)
#define GB     32     // batches per group
#define NTHR   512
#define RING   6      // h/partial ring depth; inv period 4 <= RING-2

typedef __attribute__((ext_vector_type(8))) short bf16x8;
typedef __attribute__((ext_vector_type(4))) float f32x4;
typedef unsigned int uint32;
typedef unsigned long long u64;

// ---- d_ws layout ----
// shorts [0, 3*WMAT)            : lo weights W0l,W1l,W2l
// shorts [3*WMAT, 6*WMAT)       : hi weights (read ONCE at init; overlaid by rings after)
// bytes  [6MB, 12MB)            : h1ring [RING][GRPS][16384] u32, then h2ring same (overlay of hi)
// bytes  [12MB, +589824)        : FC partials [GRPS][RING][96][32] f32
// bytes  [then, +32KB)          : flags, one u32 per WG, stride 32 u32 (128B)
#define WMAT_ELEMS 1048576
#define HI_BASE    (3 * WMAT_ELEMS)
#define RING_OFF   (6 * 1024 * 1024)
#define HBUF_UINTS 16384
#define H1_UINTS   (RING * GRPS * HBUF_UINTS)
#define PART_OFF   (12 * 1024 * 1024)
#define PART_BYTES (GRPS * RING * 96 * 32 * 4)
#define FLAG_OFF   (PART_OFF + PART_BYTES)
#define FLAG_STRIDE 32
#define FLAG_BYTES (256 * FLAG_STRIDE * 4)
#define SMEM_BYTES 153600

__device__ __forceinline__ unsigned short f2bf(float x){
    unsigned int u = __float_as_uint(x);
    u = (u + 0x7fffu + ((u >> 16) & 1u)) >> 16;   // RNE
    return (unsigned short)u;
}
__device__ __forceinline__ float bf2f(unsigned short h){
    return __uint_as_float(((unsigned int)h) << 16);
}
__device__ __forceinline__ float sigm(float v){ return 1.0f / (1.0f + __expf(-v)); }
__device__ __forceinline__ float tanh_(float v){
    float e = __expf(2.0f * v);
    return (e - 1.0f) / (e + 1.0f);
}

// Pack W[2048][512] fp32 -> bf16 hi/lo in MFMA A-frag order.
// element(jg, kt, lane, jj): row = g*512 + j*16 + (lane&15), k = kt*32 + ((lane>>4)&3)*8 + jj
__global__ void prep_weights(const float* __restrict__ W0,
                             const float* __restrict__ W1,
                             const float* __restrict__ W2,
                             short* __restrict__ wp)
{
    const int mat = blockIdx.y;
    const float* src = (mat == 0) ? W0 : ((mat == 1) ? W1 : W2);
    short* dl = wp + (size_t)mat * WMAT_ELEMS;
    short* dh = wp + HI_BASE + (size_t)mat * WMAT_ELEMS;
    const int jg = blockIdx.x;            // j*4 + g
    const int j = jg >> 2, g = jg & 3;
    for (int rep = 0; rep < 2; ++rep){
        int task = rep * NTHR + (int)threadIdx.x;
        int kt = task >> 6, l = task & 63;
        int row = g * 512 + j * 16 + (l & 15);
        int k0  = kt * 32 + ((l >> 4) & 3) * 8;
        const float* s = src + (size_t)row * HID + k0;
        bf16x8 vh, vl;
        #pragma unroll
        for (int e = 0; e < 8; ++e){
            float v = s[e];
            unsigned short hb = f2bf(v);
            vh[e] = (short)hb;
            vl[e] = (short)f2bf(v - bf2f(hb));
        }
        size_t o = ((size_t)(jg * 16 + kt) * 64 + l) * 8;
        *(bf16x8*)(dh + o) = vh;
        *(bf16x8*)(dl + o) = vl;
    }
}

__global__ void __launch_bounds__(NTHR, 2)
lstm2_mfma(const float* __restrict__ x,
           const float* __restrict__ Wih0,
           const float* __restrict__ bih0, const float* __restrict__ bhh0,
           const float* __restrict__ bih1, const float* __restrict__ bhh1,
           const float* __restrict__ Wfc,  const float* __restrict__ bfc,
           float* __restrict__ out, char* __restrict__ ws)
{
    extern __shared__ char smem[];
    short* lh1h = (short*)smem;             // 4 x 32KB h staging
    short* lh1l = lh1h + 16384;
    short* lh2h = lh1l + 16384;
    short* lh2l = lh2h + 16384;
    float* g1   = (float*)(smem + 131072);  // 8KB
    float* g2   = g1 + 2048;                // 8KB
    float* fcb  = g2 + 2048;                // 6KB

    const short* Wp  = (const short*)ws;
    const short* W0l = Wp;
    const short* W1l = Wp + WMAT_ELEMS;
    const short* W2l = Wp + 2 * WMAT_ELEMS;
    const short* Whi = Wp + HI_BASE;
    uint32* h1ring = (uint32*)(ws + RING_OFF);
    uint32* h2ring = h1ring + H1_UINTS;
    float*  part   = (float*)(ws + PART_OFF);
    uint32* flags  = (uint32*)(ws + FLAG_OFF);

    const int tid = threadIdx.x;
    const int wg  = blockIdx.x;
    const int grp = wg >> 5;          // wg&7==j&7 -> weight slices co-locate per XCD
    const int j   = wg & 31;

    const int wv = tid >> 6, lane = tid & 63;
    const int g  = wv >> 1, kh = wv & 1;
    const int ablk = (j * 4 + g) * 16;

    const int q  = tid >> 5, b = tid & 31;
    const int qg = j * 16 + q;
    const int nn = b >> 4, bl = b & 15;
    const int eidx = (((qg >> 5) * 2 + nn) * 64 + ((qg >> 3) & 3) * 16 + bl) * 8 + (qg & 7);

    float bias1[4], bias2[4], wxr[4][3];
    #pragma unroll
    for (int gg = 0; gg < 4; ++gg){
        int row = gg * 512 + qg;
        bias1[gg] = bih0[row] + bhh0[row];
        bias2[gg] = bih1[row] + bhh1[row];
        wxr[gg][0] = Wih0[row * 3 + 0];
        wxr[gg][1] = Wih0[row * 3 + 1];
        wxr[gg][2] = Wih0[row * 3 + 2];
    }
    const float wf0 = Wfc[qg], wf1 = Wfc[512 + qg], wf2 = Wfc[1024 + qg];
    const int   didx = j * 3 + (tid < 3 ? tid : 0);
    const float bfcv = bfc[didx >> 5];

    // hi-weight fragments (attempt VGPR residency; worst case they reload from L2)
    bf16x8 w0h[8], w1h[8], w2h[8];
    #pragma unroll
    for (int ks = 0; ks < 8; ++ks){
        const int kt = kh * 8 + ks;
        const size_t ao = ((size_t)(ablk + kt) * 64 + lane) * 8;
        w0h[ks] = *(const bf16x8*)(Whi + ao);
        w1h[ks] = *(const bf16x8*)(Whi + WMAT_ELEMS + ao);
        w2h[ks] = *(const bf16x8*)(Whi + 2 * WMAT_ELEMS + ao);
    }

    // ---- init barrier: hi reads done (release store waits them) before rings overlay hi ----
    if (tid == 0)
        __hip_atomic_store(flags + wg * FLAG_STRIDE, 1u, __ATOMIC_RELEASE, __HIP_MEMORY_SCOPE_AGENT);
    if (tid < 64){
        bool ok;
        do {
            ok = true;
            #pragma unroll
            for (int r = 0; r < 4; ++r){
                uint32 v = __hip_atomic_load(flags + (r * 64 + tid) * FLAG_STRIDE,
                                             __ATOMIC_RELAXED, __HIP_MEMORY_SCOPE_AGENT);
                ok &= (v >= 1u);
            }
        } while (!__all(ok));
    }
    __syncthreads();

    float c1 = 0.f, c2 = 0.f;

    for (int p = 0; p <= SEQT; ++p){
        // ---- A: group-barrier detect (phase p-1 done) + periodic cache invalidate ----
        if (p > 0 && tid < 64){
            const uint32 need = (uint32)(p + 1);
            const uint32* f = flags + grp * SLICES * FLAG_STRIDE + tid * FLAG_STRIDE;
            while (true){
                uint32 v = (tid < SLICES)
                    ? __hip_atomic_load(f, __ATOMIC_RELAXED, __HIP_MEMORY_SCOPE_AGENT)
                    : 0xffffffffu;
                if (__all(v >= need)) break;
            }
        }
        if ((p & 3) == 0) __builtin_amdgcn_fence(__ATOMIC_ACQUIRE, "agent");
        __syncthreads();

        // ---- B: stage h via CACHED loads (fresh ring addresses each phase) ----
        const int slot1 = (p + RING - 1) % RING;   // h1(p-1)
        const int slot2 = (p + RING - 2) % RING;   // h2(p-2)
        {
            const u64* s1 = (const u64*)(h1ring + (slot1 * GRPS + grp) * HBUF_UINTS);
            const u64* s2 = (const u64*)(h2ring + (slot2 * GRPS + grp) * HBUF_UINTS);
            uint32* d1h = (uint32*)lh1h; uint32* d1l = (uint32*)lh1l;
            uint32* d2h = (uint32*)lh2h; uint32* d2l = (uint32*)lh2l;

            u64 v[16];
            if (p >= 1){
                #pragma unroll
                for (int c = 0; c < 16; ++c) v[c] = s1[c * 512 + tid];
            } else {
                #pragma unroll
                for (int c = 0; c < 16; ++c) v[c] = 0ull;
            }

            // deferred-FC loads for t=p-2 (issued early, consumed below)
            float4 dp[8];
            const bool dodef = (p >= 2) && (tid < 3);
            if (dodef){
                const float4* pr = (const float4*)(part +
                    (((size_t)grp * RING + (size_t)((p + RING - 2) % RING)) * 96 + didx) * 32);
                #pragma unroll
                for (int c = 0; c < 8; ++c) dp[c] = pr[c];
            }

            #pragma unroll
            for (int c = 0; c < 16; ++c){
                uint32 a = (uint32)v[c], bo_ = (uint32)(v[c] >> 32);
                d1h[c * 512 + tid] = __builtin_amdgcn_perm(bo_, a, 0x05040100u);
                d1l[c * 512 + tid] = __builtin_amdgcn_perm(bo_, a, 0x07060302u);
            }
            if (p >= 2){
                #pragma unroll
                for (int c = 0; c < 16; ++c) v[c] = s2[c * 512 + tid];
            } else {
                #pragma unroll
                for (int c = 0; c < 16; ++c) v[c] = 0ull;
            }
            #pragma unroll
            for (int c = 0; c < 16; ++c){
                uint32 a = (uint32)v[c], bo_ = (uint32)(v[c] >> 32);
                d2h[c * 512 + tid] = __builtin_amdgcn_perm(bo_, a, 0x05040100u);
                d2l[c * 512 + tid] = __builtin_amdgcn_perm(bo_, a, 0x07060302u);
            }

            if (dodef){
                float s = 0.f;
                #pragma unroll
                for (int c = 0; c < 8; ++c) s += dp[c].x + dp[c].y + dp[c].z + dp[c].w;
                int dd = didx >> 5, bb = didx & 31;
                __hip_atomic_store(out + ((size_t)(grp * GB + bb) * SEQT + (p - 2)) * 3 + dd,
                                   s + bfcv, __ATOMIC_RELAXED, __HIP_MEMORY_SCOPE_AGENT);
            }
        }
        __syncthreads();

        // ---- C: MFMA (bf16 3-mul split): gates1 = Whh0*h1 ; gates2 = Wih1*h1 + Whh1*h2 ----
        f32x4 acc1[2] = {{0.f,0.f,0.f,0.f},{0.f,0.f,0.f,0.f}};
        f32x4 acc2[2] = {{0.f,0.f,0.f,0.f},{0.f,0.f,0.f,0.f}};
        #pragma unroll
        for (int ks = 0; ks < 8; ++ks){
            const int kt = kh * 8 + ks;
            const size_t ao = ((size_t)(ablk + kt) * 64 + lane) * 8;
            bf16x8 a0l = *(const bf16x8*)(W0l + ao);
            bf16x8 a1l = *(const bf16x8*)(W1l + ao);
            bf16x8 a2l = *(const bf16x8*)(W2l + ao);
            #pragma unroll
            for (int n = 0; n < 2; ++n){
                const int bo = ((kt * 2 + n) * 64 + lane) * 8;
                bf16x8 b1h = *(const bf16x8*)(lh1h + bo);
                bf16x8 b1l = *(const bf16x8*)(lh1l + bo);
                bf16x8 b2h = *(const bf16x8*)(lh2h + bo);
                bf16x8 b2l = *(const bf16x8*)(lh2l + bo);
                acc1[n] = __builtin_amdgcn_mfma_f32_16x16x32_bf16(w0h[ks], b1h, acc1[n], 0, 0, 0);
                acc1[n] = __builtin_amdgcn_mfma_f32_16x16x32_bf16(w0h[ks], b1l, acc1[n], 0, 0, 0);
                acc1[n] = __builtin_amdgcn_mfma_f32_16x16x32_bf16(a0l,     b1h, acc1[n], 0, 0, 0);
                acc2[n] = __builtin_amdgcn_mfma_f32_16x16x32_bf16(w1h[ks], b1h, acc2[n], 0, 0, 0);
                acc2[n] = __builtin_amdgcn_mfma_f32_16x16x32_bf16(w1h[ks], b1l, acc2[n], 0, 0, 0);
                acc2[n] = __builtin_amdgcn_mfma_f32_16x16x32_bf16(a1l,     b1h, acc2[n], 0, 0, 0);
                acc2[n] = __builtin_amdgcn_mfma_f32_16x16x32_bf16(w2h[ks], b2h, acc2[n], 0, 0, 0);
                acc2[n] = __builtin_amdgcn_mfma_f32_16x16x32_bf16(w2h[ks], b2l, acc2[n], 0, 0, 0);
                acc2[n] = __builtin_amdgcn_mfma_f32_16x16x32_bf16(a2l,     b2h, acc2[n], 0, 0, 0);
            }
        }

        // ---- D: combine k-halves in LDS ----
        if (kh == 0){
            #pragma unroll
            for (int n = 0; n < 2; ++n)
                #pragma unroll
                for (int r = 0; r < 4; ++r){
                    int qrow = (lane >> 4) * 4 + r;
                    int idx = ((g * 2 + n) * 16 + qrow) * 16 + (lane & 15);
                    g1[idx] = acc1[n][r];
                    g2[idx] = acc2[n][r];
                }
        }
        __syncthreads();
        if (kh == 1){
            #pragma unroll
            for (int n = 0; n < 2; ++n)
                #pragma unroll
                for (int r = 0; r < 4; ++r){
                    int qrow = (lane >> 4) * 4 + r;
                    int idx = ((g * 2 + n) * 16 + qrow) * 16 + (lane & 15);
                    g1[idx] += acc1[n][r];
                    g2[idx] += acc2[n][r];
                }
        }
        __syncthreads();

        // ---- E: pointwise L1 (t=p) ----
        if (p < SEQT){
            float gt0 = bias1[0] + g1[((0 * 2 + nn) * 16 + q) * 16 + bl];
            float gt1 = bias1[1] + g1[((1 * 2 + nn) * 16 + q) * 16 + bl];
            float gt2 = bias1[2] + g1[((2 * 2 + nn) * 16 + q) * 16 + bl];
            float gt3 = bias1[3] + g1[((3 * 2 + nn) * 16 + q) * 16 + bl];
            const float* xp = x + ((size_t)(grp * GB + b) * SEQT + p) * 3;
            float x0 = xp[0], x1 = xp[1], x2 = xp[2];
            gt0 += wxr[0][0] * x0 + wxr[0][1] * x1 + wxr[0][2] * x2;
            gt1 += wxr[1][0] * x0 + wxr[1][1] * x1 + wxr[1][2] * x2;
            gt2 += wxr[2][0] * x0 + wxr[2][1] * x1 + wxr[2][2] * x2;
            gt3 += wxr[3][0] * x0 + wxr[3][1] * x1 + wxr[3][2] * x2;
            float ii = sigm(gt0), ff = sigm(gt1), gv = tanh_(gt2), oo = sigm(gt3);
            c1 = ff * c1 + ii * gv;
            float h = oo * tanh_(c1);
            unsigned short hb = f2bf(h);
            unsigned short lb = f2bf(h - bf2f(hb));
            uint32 pv = (uint32)hb | ((uint32)lb << 16);
            __hip_atomic_store(h1ring + ((p % RING) * GRPS + grp) * HBUF_UINTS + eidx, pv,
                               __ATOMIC_RELAXED, __HIP_MEMORY_SCOPE_AGENT);
        }

        // ---- pointwise L2 (t=p-1) + FC partial staging ----
        if (p >= 1){
            float gt0 = bias2[0] + g2[((0 * 2 + nn) * 16 + q) * 16 + bl];
            float gt1 = bias2[1] + g2[((1 * 2 + nn) * 16 + q) * 16 + bl];
            float gt2 = bias2[2] + g2[((2 * 2 + nn) * 16 + q) * 16 + bl];
            float gt3 = bias2[3] + g2[((3 * 2 + nn) * 16 + q) * 16 + bl];
            float ii = sigm(gt0), ff = sigm(gt1), gv = tanh_(gt2), oo = sigm(gt3);
            c2 = ff * c2 + ii * gv;
            float h = oo * tanh_(c2);
            unsigned short hb = f2bf(h);
            unsigned short lb = f2bf(h - bf2f(hb));
            uint32 pv = (uint32)hb | ((uint32)lb << 16);
            __hip_atomic_store(h2ring + (((p - 1) % RING) * GRPS + grp) * HBUF_UINTS + eidx, pv,
                               __ATOMIC_RELAXED, __HIP_MEMORY_SCOPE_AGENT);
            fcb[0 * 512 + tid] = wf0 * h;
            fcb[1 * 512 + tid] = wf1 * h;
            fcb[2 * 512 + tid] = wf2 * h;
        }
        __syncthreads();
        if (p >= 1 && tid < 96){
            int d = tid >> 5;
            float s = 0.f;
            #pragma unroll
            for (int qq = 0; qq < 16; ++qq) s += fcb[d * 512 + qq * 32 + (tid & 31)];
            __hip_atomic_store(part + (((size_t)grp * RING + (size_t)((p + RING - 1) % RING)) * 96
                                       + tid) * 32 + j, s,
                               __ATOMIC_RELAXED, __HIP_MEMORY_SCOPE_AGENT);
        }
        __syncthreads();   // all waves drained (vmcnt0 at barrier) before arrival

        // ---- F: arrival ----
        if (tid == 0)
            __hip_atomic_store(flags + wg * FLAG_STRIDE, (uint32)(p + 2),
                               __ATOMIC_RELEASE, __HIP_MEMORY_SCOPE_AGENT);
    }

    // ---- drain: FC for t = SEQT-1 after final group barrier ----
    if (tid < 64){
        const uint32 need = (uint32)(SEQT + 2);
        const uint32* f = flags + grp * SLICES * FLAG_STRIDE + tid * FLAG_STRIDE;
        while (true){
            uint32 v = (tid < SLICES)
                ? __hip_atomic_load(f, __ATOMIC_RELAXED, __HIP_MEMORY_SCOPE_AGENT)
                : 0xffffffffu;
            if (__all(v >= need)) break;
        }
    }
    __builtin_amdgcn_fence(__ATOMIC_ACQUIRE, "agent");
    __syncthreads();
    if (tid < 3){
        const float4* pr = (const float4*)(part +
            (((size_t)grp * RING + (size_t)((SEQT - 1) % RING)) * 96 + didx) * 32);
        float s = 0.f;
        #pragma unroll
        for (int c = 0; c < 8; ++c){ float4 t4 = pr[c]; s += t4.x + t4.y + t4.z + t4.w; }
        int dd = didx >> 5, bb = didx & 31;
        __hip_atomic_store(out + ((size_t)(grp * GB + bb) * SEQT + (SEQT - 1)) * 3 + dd,
                           s + bfcv, __ATOMIC_RELAXED, __HIP_MEMORY_SCOPE_AGENT);
    }
}

extern "C" void kernel_launch(void* const* d_in, const int* in_sizes, int n_in,
                              void* d_out, int out_size, void* d_ws, size_t ws_size,
                              hipStream_t stream)
{
    (void)in_sizes; (void)n_in; (void)ws_size; (void)out_size;

    const float* x    = (const float*)d_in[0];
    const float* Wih0 = (const float*)d_in[1];
    const float* Whh0 = (const float*)d_in[2];
    const float* bih0 = (const float*)d_in[3];
    const float* bhh0 = (const float*)d_in[4];
    const float* Wih1 = (const float*)d_in[5];
    const float* Whh1 = (const float*)d_in[6];
    const float* bih1 = (const float*)d_in[7];
    const float* bhh1 = (const float*)d_in[8];
    const float* Wfc  = (const float*)d_in[9];
    const float* bfc  = (const float*)d_in[10];
    float* out = (float*)d_out;
    char*  ws  = (char*)d_ws;

    // zero the flag array (the only state that must start at 0)
    hipMemsetAsync(ws + FLAG_OFF, 0, FLAG_BYTES, stream);

    // pack weights (re-done every launch; d_ws is re-poisoned by the harness)
    prep_weights<<<dim3(128, 3), NTHR, 0, stream>>>(Whh0, Wih1, Whh1, (short*)ws);

    hipFuncSetAttribute((const void*)lstm2_mfma,
                        hipFuncAttributeMaxDynamicSharedMemorySize, SMEM_BYTES);

    void* args[] = { (void*)&x, (void*)&Wih0, (void*)&bih0, (void*)&bhh0,
                     (void*)&bih1, (void*)&bhh1, (void*)&Wfc, (void*)&bfc,
                     (void*)&out, (void*)&ws };
    hipLaunchCooperativeKernel((const void*)lstm2_mfma, dim3(GRPS * SLICES), dim3(NTHR),
                               args, SMEM_BYTES, stream);
}

// Round 6
// 15880.992 us; speedup vs baseline: 1.3309x; 1.3309x over previous
//
#include <hip/hip_runtime.h>
#include <stdint.h>

#define SEQT   512
#define HID    512
#define GRPS   8      // batch groups (32 batches each)
#define SLICES 32     // h-slices per group (64 gate rows each)
#define GB     32     // batches per group
#define NTHR   512

typedef __attribute__((ext_vector_type(8))) short bf16x8;
typedef __attribute__((ext_vector_type(4))) float f32x4;
typedef unsigned int uint32;
typedef unsigned long long u64;

// ---- d_ws layout (bytes) ----
// [0, 6MB)        lo weights W0l,W1l,W2l (bf16, A-frag order)
// [6MB, 12MB)     hi weights W0h,W1h,W2h
// [12MB, 13MB)    h1 packed dbuf [2][GRPS][16384] u32 (hi|lo<<16)
// [13MB, 14MB)    h2 packed dbuf
// [14MB, +192KB)  FC partials [GRPS][2][96][32] f32
// [then, +32KB)   flags, one u32 per WG, stride 128B
#define WM          1048576
#define HI_BASE     (3 * WM)
#define H1_OFF      (12 * 1024 * 1024)
#define H2_OFF      (13 * 1024 * 1024)
#define HBUF_UINTS  16384
#define PART_OFF    (14 * 1024 * 1024)
#define PART_BYTES  (GRPS * 2 * 96 * 32 * 4)
#define FLAG_OFF    (PART_OFF + PART_BYTES)
#define FLAG_STRIDE 32
#define FLAG_BYTES  (256 * FLAG_STRIDE * 4)
#define SMEM_BYTES  153600

__device__ __forceinline__ unsigned short f2bf(float x){
    unsigned int u = __float_as_uint(x);
    u = (u + 0x7fffu + ((u >> 16) & 1u)) >> 16;   // RNE
    return (unsigned short)u;
}
__device__ __forceinline__ float bf2f(unsigned short h){
    return __uint_as_float(((unsigned int)h) << 16);
}
__device__ __forceinline__ float sigm(float v){ return 1.0f / (1.0f + __expf(-v)); }
__device__ __forceinline__ float tanh_(float v){
    float e = __expf(2.0f * v);
    return (e - 1.0f) / (e + 1.0f);
}

// Pack W[2048][512] fp32 -> bf16 hi/lo in MFMA A-frag order.
// element(jg, kt, lane, jj): row = g*512 + j*16 + (lane&15), k = kt*32 + ((lane>>4)&3)*8 + jj
__global__ void prep_weights(const float* __restrict__ W0,
                             const float* __restrict__ W1,
                             const float* __restrict__ W2,
                             short* __restrict__ wp)
{
    const int mat = blockIdx.y;
    const float* src = (mat == 0) ? W0 : ((mat == 1) ? W1 : W2);
    short* dl = wp + (size_t)mat * WM;
    short* dh = wp + HI_BASE + (size_t)mat * WM;
    const int jg = blockIdx.x;            // j*4 + g
    const int j = jg >> 2, g = jg & 3;
    for (int rep = 0; rep < 2; ++rep){
        int task = rep * NTHR + (int)threadIdx.x;
        int kt = task >> 6, l = task & 63;
        int row = g * 512 + j * 16 + (l & 15);
        int k0  = kt * 32 + ((l >> 4) & 3) * 8;
        const float* s = src + (size_t)row * HID + k0;
        bf16x8 vh, vl;
        #pragma unroll
        for (int e = 0; e < 8; ++e){
            float v = s[e];
            unsigned short hb = f2bf(v);
            vh[e] = (short)hb;
            vl[e] = (short)f2bf(v - bf2f(hb));
        }
        size_t o = ((size_t)(jg * 16 + kt) * 64 + l) * 8;
        *(bf16x8*)(dh + o) = vh;
        *(bf16x8*)(dl + o) = vl;
    }
}

__global__ void __launch_bounds__(NTHR, 2)
lstm2_mfma(const float* __restrict__ x,
           const float* __restrict__ Wih0,
           const float* __restrict__ bih0, const float* __restrict__ bhh0,
           const float* __restrict__ bih1, const float* __restrict__ bhh1,
           const float* __restrict__ Wfc,  const float* __restrict__ bfc,
           float* __restrict__ out, char* __restrict__ ws)
{
    extern __shared__ char smem[];
    short* lh1h = (short*)smem;             // 4 x 32KB unpacked h staging
    short* lh1l = lh1h + 16384;
    short* lh2h = lh1l + 16384;
    short* lh2l = lh2h + 16384;
    float* g1   = (float*)(smem + 131072);  // 8 tiles x 16 x 16 = 8KB
    float* g2   = g1 + 2048;                // 8KB
    float* fcb  = g2 + 2048;                // 6KB

    const short* Wp = (const short*)ws;
    uint32* h1p  = (uint32*)(ws + H1_OFF);
    uint32* h2p  = (uint32*)(ws + H2_OFF);
    float*  part = (float*)(ws + PART_OFF);
    uint32* flags = (uint32*)(ws + FLAG_OFF);

    const int tid = threadIdx.x;
    const int wg  = blockIdx.x;
    const int grp = wg >> 5;          // wg&7==j&7 -> weight slices co-locate per XCD
    const int j   = wg & 31;

    // MFMA mapping: 8 waves = 4 gates x 2 batch-halves, each FULL K (no combine step)
    const int wv = tid >> 6, lane = tid & 63;
    const int g  = wv & 3, n = wv >> 2;
    const int ablk = (j * 4 + g) * 16;

    // pointwise mapping: 16 q x 32 b
    const int q  = tid >> 5, b = tid & 31;
    const int qg = j * 16 + q;
    const int nn = b >> 4, bl = b & 15;
    const int eidx = (((qg >> 5) * 2 + nn) * 64 + ((qg >> 3) & 3) * 16 + bl) * 8 + (qg & 7);

    float bias1[4], bias2[4], wxr[4][3];
    #pragma unroll
    for (int gg = 0; gg < 4; ++gg){
        int row = gg * 512 + qg;
        bias1[gg] = bih0[row] + bhh0[row];
        bias2[gg] = bih1[row] + bhh1[row];
        wxr[gg][0] = Wih0[row * 3 + 0];
        wxr[gg][1] = Wih0[row * 3 + 1];
        wxr[gg][2] = Wih0[row * 3 + 2];
    }
    const float wf0 = Wfc[qg], wf1 = Wfc[512 + qg], wf2 = Wfc[1024 + qg];
    const int   didx = j * 3 + (tid < 3 ? tid : 0);   // deferred-FC output row (d*32+bb)
    const float bfcv = bfc[didx >> 5];

    float c1 = 0.f, c2 = 0.f;

    // phase p: L1 computes t=p (p<512); L2 computes t=p-1 (p>=1).
    for (int p = 0; p <= SEQT; ++p){
        // ---- A: flag barrier (all 32 WGs of my group finished phase p-1) ----
        if (p > 0 && tid < 64){
            const uint32 need = (uint32)(p + 1);
            const uint32* f = flags + grp * SLICES * FLAG_STRIDE + tid * FLAG_STRIDE;
            while (true){
                uint32 v = (tid < SLICES)
                    ? __hip_atomic_load(f, __ATOMIC_RELAXED, __HIP_MEMORY_SCOPE_AGENT)
                    : 0xffffffffu;
                if (__all(v >= need)) break;
            }
        }
        __builtin_amdgcn_fence(__ATOMIC_ACQUIRE, "agent");   // r3-proven: cheap, selective
        __syncthreads();

        // ---- B: stage h1(p-1), h2(p-2) via plain cached loads; deferred FC for t=p-2 ----
        {
            const u64* s1 = (const u64*)(h1p + (((p + 1) & 1) * GRPS + grp) * HBUF_UINTS);
            const u64* s2 = (const u64*)(h2p + ((p & 1) * GRPS + grp) * HBUF_UINTS);
            uint32* d1h = (uint32*)lh1h; uint32* d1l = (uint32*)lh1l;
            uint32* d2h = (uint32*)lh2h; uint32* d2l = (uint32*)lh2l;

            u64 v[16];
            if (p >= 1){
                #pragma unroll
                for (int c = 0; c < 16; ++c) v[c] = s1[c * 512 + tid];
            } else {
                #pragma unroll
                for (int c = 0; c < 16; ++c) v[c] = 0ull;
            }

            float4 dp[8];
            const bool dodef = (p >= 2) && (tid < 3);
            if (dodef){
                const float4* pr = (const float4*)(part +
                    (((size_t)grp * 2 + ((p + 1) & 1)) * 96 + didx) * 32);
                #pragma unroll
                for (int c = 0; c < 8; ++c) dp[c] = pr[c];
            }

            #pragma unroll
            for (int c = 0; c < 16; ++c){
                uint32 a = (uint32)v[c], bo_ = (uint32)(v[c] >> 32);
                d1h[c * 512 + tid] = __builtin_amdgcn_perm(bo_, a, 0x05040100u);
                d1l[c * 512 + tid] = __builtin_amdgcn_perm(bo_, a, 0x07060302u);
            }
            if (p >= 2){
                #pragma unroll
                for (int c = 0; c < 16; ++c) v[c] = s2[c * 512 + tid];
            } else {
                #pragma unroll
                for (int c = 0; c < 16; ++c) v[c] = 0ull;
            }
            #pragma unroll
            for (int c = 0; c < 16; ++c){
                uint32 a = (uint32)v[c], bo_ = (uint32)(v[c] >> 32);
                d2h[c * 512 + tid] = __builtin_amdgcn_perm(bo_, a, 0x05040100u);
                d2l[c * 512 + tid] = __builtin_amdgcn_perm(bo_, a, 0x07060302u);
            }

            if (dodef){
                float s = 0.f;
                #pragma unroll
                for (int c = 0; c < 8; ++c) s += dp[c].x + dp[c].y + dp[c].z + dp[c].w;
                int dd = didx >> 5, bb = didx & 31;
                __hip_atomic_store(out + ((size_t)(grp * GB + bb) * SEQT + (p - 2)) * 3 + dd,
                                   s + bfcv, __ATOMIC_RELAXED, __HIP_MEMORY_SCOPE_AGENT);
            }
        }
        __syncthreads();

        // ---- C: MFMA, full K per wave (bf16 3-mul split) ----
        f32x4 acc1 = {0.f,0.f,0.f,0.f};
        f32x4 acc2 = {0.f,0.f,0.f,0.f};
        #pragma unroll 2
        for (int kt = 0; kt < 16; ++kt){
            const size_t ao = (size_t)(ablk + kt) * 512 + lane * 8;
            bf16x8 a0h = *(const bf16x8*)(Wp + HI_BASE + ao);
            bf16x8 a1h = *(const bf16x8*)(Wp + HI_BASE + WM + ao);
            bf16x8 a2h = *(const bf16x8*)(Wp + HI_BASE + 2 * WM + ao);
            bf16x8 a0l = *(const bf16x8*)(Wp + ao);
            bf16x8 a1l = *(const bf16x8*)(Wp + WM + ao);
            bf16x8 a2l = *(const bf16x8*)(Wp + 2 * WM + ao);
            const int bo = (kt * 2 + n) * 512 + lane * 8;
            bf16x8 b1h = *(const bf16x8*)(lh1h + bo);
            bf16x8 b1l = *(const bf16x8*)(lh1l + bo);
            bf16x8 b2h = *(const bf16x8*)(lh2h + bo);
            bf16x8 b2l = *(const bf16x8*)(lh2l + bo);
            acc1 = __builtin_amdgcn_mfma_f32_16x16x32_bf16(a0h, b1h, acc1, 0, 0, 0);
            acc1 = __builtin_amdgcn_mfma_f32_16x16x32_bf16(a0h, b1l, acc1, 0, 0, 0);
            acc1 = __builtin_amdgcn_mfma_f32_16x16x32_bf16(a0l, b1h, acc1, 0, 0, 0);
            acc2 = __builtin_amdgcn_mfma_f32_16x16x32_bf16(a1h, b1h, acc2, 0, 0, 0);
            acc2 = __builtin_amdgcn_mfma_f32_16x16x32_bf16(a1h, b1l, acc2, 0, 0, 0);
            acc2 = __builtin_amdgcn_mfma_f32_16x16x32_bf16(a1l, b1h, acc2, 0, 0, 0);
            acc2 = __builtin_amdgcn_mfma_f32_16x16x32_bf16(a2h, b2h, acc2, 0, 0, 0);
            acc2 = __builtin_amdgcn_mfma_f32_16x16x32_bf16(a2h, b2l, acc2, 0, 0, 0);
            acc2 = __builtin_amdgcn_mfma_f32_16x16x32_bf16(a2l, b2h, acc2, 0, 0, 0);
        }

        // ---- D: each wave writes its (gate, batch-half) tile; ONE sync ----
        {
            const int base = (g * 2 + n) * 256 + (lane & 15);
            #pragma unroll
            for (int r = 0; r < 4; ++r){
                int row = (lane >> 4) * 4 + r;
                g1[base + row * 16] = acc1[r];
                g2[base + row * 16] = acc2[r];
            }
        }
        __syncthreads();

        // ---- E: pointwise L1 (t=p) ----
        if (p < SEQT){
            float gt0 = bias1[0] + g1[(0 * 2 + nn) * 256 + q * 16 + bl];
            float gt1 = bias1[1] + g1[(1 * 2 + nn) * 256 + q * 16 + bl];
            float gt2 = bias1[2] + g1[(2 * 2 + nn) * 256 + q * 16 + bl];
            float gt3 = bias1[3] + g1[(3 * 2 + nn) * 256 + q * 16 + bl];
            const float* xp = x + ((size_t)(grp * GB + b) * SEQT + p) * 3;
            float x0 = xp[0], x1 = xp[1], x2 = xp[2];
            gt0 += wxr[0][0] * x0 + wxr[0][1] * x1 + wxr[0][2] * x2;
            gt1 += wxr[1][0] * x0 + wxr[1][1] * x1 + wxr[1][2] * x2;
            gt2 += wxr[2][0] * x0 + wxr[2][1] * x1 + wxr[2][2] * x2;
            gt3 += wxr[3][0] * x0 + wxr[3][1] * x1 + wxr[3][2] * x2;
            float ii = sigm(gt0), ff = sigm(gt1), gv = tanh_(gt2), oo = sigm(gt3);
            c1 = ff * c1 + ii * gv;
            float h = oo * tanh_(c1);
            unsigned short hb = f2bf(h);
            unsigned short lb = f2bf(h - bf2f(hb));
            uint32 pv = (uint32)hb | ((uint32)lb << 16);
            __hip_atomic_store(h1p + ((p & 1) * GRPS + grp) * HBUF_UINTS + eidx, pv,
                               __ATOMIC_RELAXED, __HIP_MEMORY_SCOPE_AGENT);
        }

        // ---- pointwise L2 (t=p-1) + FC partial staging ----
        if (p >= 1){
            float gt0 = bias2[0] + g2[(0 * 2 + nn) * 256 + q * 16 + bl];
            float gt1 = bias2[1] + g2[(1 * 2 + nn) * 256 + q * 16 + bl];
            float gt2 = bias2[2] + g2[(2 * 2 + nn) * 256 + q * 16 + bl];
            float gt3 = bias2[3] + g2[(3 * 2 + nn) * 256 + q * 16 + bl];
            float ii = sigm(gt0), ff = sigm(gt1), gv = tanh_(gt2), oo = sigm(gt3);
            c2 = ff * c2 + ii * gv;
            float h = oo * tanh_(c2);
            unsigned short hb = f2bf(h);
            unsigned short lb = f2bf(h - bf2f(hb));
            uint32 pv = (uint32)hb | ((uint32)lb << 16);
            __hip_atomic_store(h2p + (((p - 1) & 1) * GRPS + grp) * HBUF_UINTS + eidx, pv,
                               __ATOMIC_RELAXED, __HIP_MEMORY_SCOPE_AGENT);
            fcb[0 * 512 + tid] = wf0 * h;
            fcb[1 * 512 + tid] = wf1 * h;
            fcb[2 * 512 + tid] = wf2 * h;
        }
        __syncthreads();
        if (p >= 1 && tid < 96){
            int d = tid >> 5;
            float s = 0.f;
            #pragma unroll
            for (int qq = 0; qq < 16; ++qq) s += fcb[d * 512 + qq * 32 + (tid & 31)];
            __hip_atomic_store(part + (((size_t)grp * 2 + (p & 1)) * 96 + tid) * 32 + j, s,
                               __ATOMIC_RELAXED, __HIP_MEMORY_SCOPE_AGENT);
        }
        __syncthreads();   // each wave drains vmcnt(0) at barrier -> all stores visible

        // ---- F: arrival ----
        if (tid == 0)
            __hip_atomic_store(flags + wg * FLAG_STRIDE, (uint32)(p + 2),
                               __ATOMIC_RELEASE, __HIP_MEMORY_SCOPE_AGENT);
    }

    // ---- drain: FC for t = SEQT-1 (partials written at phase SEQT) ----
    if (tid < 64){
        const uint32 need = (uint32)(SEQT + 2);
        const uint32* f = flags + grp * SLICES * FLAG_STRIDE + tid * FLAG_STRIDE;
        while (true){
            uint32 v = (tid < SLICES)
                ? __hip_atomic_load(f, __ATOMIC_RELAXED, __HIP_MEMORY_SCOPE_AGENT)
                : 0xffffffffu;
            if (__all(v >= need)) break;
        }
    }
    __builtin_amdgcn_fence(__ATOMIC_ACQUIRE, "agent");
    __syncthreads();
    if (tid < 3){
        const float4* pr = (const float4*)(part +
            (((size_t)grp * 2 + (SEQT & 1)) * 96 + didx) * 32);
        float s = 0.f;
        #pragma unroll
        for (int c = 0; c < 8; ++c){ float4 t4 = pr[c]; s += t4.x + t4.y + t4.z + t4.w; }
        int dd = didx >> 5, bb = didx & 31;
        __hip_atomic_store(out + ((size_t)(grp * GB + bb) * SEQT + (SEQT - 1)) * 3 + dd,
                           s + bfcv, __ATOMIC_RELAXED, __HIP_MEMORY_SCOPE_AGENT);
    }
}

extern "C" void kernel_launch(void* const* d_in, const int* in_sizes, int n_in,
                              void* d_out, int out_size, void* d_ws, size_t ws_size,
                              hipStream_t stream)
{
    (void)in_sizes; (void)n_in; (void)ws_size; (void)out_size;

    const float* x    = (const float*)d_in[0];
    const float* Wih0 = (const float*)d_in[1];
    const float* Whh0 = (const float*)d_in[2];
    const float* bih0 = (const float*)d_in[3];
    const float* bhh0 = (const float*)d_in[4];
    const float* Wih1 = (const float*)d_in[5];
    const float* Whh1 = (const float*)d_in[6];
    const float* bih1 = (const float*)d_in[7];
    const float* bhh1 = (const float*)d_in[8];
    const float* Wfc  = (const float*)d_in[9];
    const float* bfc  = (const float*)d_in[10];
    float* out = (float*)d_out;
    char*  ws  = (char*)d_ws;

    // zero the flag array (phase guards make h/partial init unnecessary; out fully overwritten)
    hipMemsetAsync(ws + FLAG_OFF, 0, FLAG_BYTES, stream);

    // pack weights (re-done every launch; d_ws is re-poisoned by the harness)
    prep_weights<<<dim3(128, 3), NTHR, 0, stream>>>(Whh0, Wih1, Whh1, (short*)ws);

    hipFuncSetAttribute((const void*)lstm2_mfma,
                        hipFuncAttributeMaxDynamicSharedMemorySize, SMEM_BYTES);

    void* args[] = { (void*)&x, (void*)&Wih0, (void*)&bih0, (void*)&bhh0,
                     (void*)&bih1, (void*)&bhh1, (void*)&Wfc, (void*)&bfc,
                     (void*)&out, (void*)&ws };
    hipLaunchCooperativeKernel((const void*)lstm2_mfma, dim3(GRPS * SLICES), dim3(NTHR),
                               args, SMEM_BYTES, stream);
}

// Round 7
// 15846.896 us; speedup vs baseline: 1.3337x; 1.0022x over previous
//
#include <hip/hip_runtime.h>
#include <stdint.h>

#define SEQT   512
#define HID    512
#define GRPS   8      // batch groups (32 batches each)
#define SLICES 32     // h-slices per group (64 gate rows each)
#define GB     32     // batches per group
#define NTHR   512

typedef __attribute__((ext_vector_type(8))) short bf16x8;
typedef __attribute__((ext_vector_type(4))) float f32x4;
typedef unsigned int uint32;

// ---- d_ws layout (bytes) ----
// [0, 6MB)        lo weights W0l,W1l,W2l (bf16, A-frag order)
// [6MB, 12MB)     hi weights W0h,W1h,W2h
// [12MB, +2MB)    h exchange, UNPACKED: h1h,h1l,h2h,h2l each [2][GRPS][16384] bf16 (512KB)
// [14MB, +192KB)  FC partials [GRPS][2][96][32] f32
// [then, +32KB)   flags, one u32 per WG, stride 128B
#define WM          1048576
#define HI_BASE     (3 * WM)
#define H_OFF       (12 * 1024 * 1024)
#define HBUF_E      16384
#define HARR_E      (2 * GRPS * HBUF_E)      // shorts per h array (512KB)
#define PART_OFF    (14 * 1024 * 1024)
#define PART_BYTES  (GRPS * 2 * 96 * 32 * 4)
#define FLAG_OFF    (PART_OFF + PART_BYTES)
#define FLAG_STRIDE 32
#define FLAG_BYTES  (256 * FLAG_STRIDE * 4)

__device__ __forceinline__ unsigned short f2bf(float x){
    unsigned int u = __float_as_uint(x);
    u = (u + 0x7fffu + ((u >> 16) & 1u)) >> 16;   // RNE
    return (unsigned short)u;
}
__device__ __forceinline__ float bf2f(unsigned short h){
    return __uint_as_float(((unsigned int)h) << 16);
}
__device__ __forceinline__ float sigm(float v){ return 1.0f / (1.0f + __expf(-v)); }
__device__ __forceinline__ float tanh_(float v){
    float e = __expf(2.0f * v);
    return (e - 1.0f) / (e + 1.0f);
}

// Pack W[2048][512] fp32 -> bf16 hi/lo in MFMA A-frag order.
// element(jg, kt, lane, jj): row = g*512 + j*16 + (lane&15), k = kt*32 + ((lane>>4)&3)*8 + jj
__global__ void prep_weights(const float* __restrict__ W0,
                             const float* __restrict__ W1,
                             const float* __restrict__ W2,
                             short* __restrict__ wp)
{
    const int mat = blockIdx.y;
    const float* src = (mat == 0) ? W0 : ((mat == 1) ? W1 : W2);
    short* dl = wp + (size_t)mat * WM;
    short* dh = wp + HI_BASE + (size_t)mat * WM;
    const int jg = blockIdx.x;            // j*4 + g
    const int j = jg >> 2, g = jg & 3;
    for (int rep = 0; rep < 2; ++rep){
        int task = rep * NTHR + (int)threadIdx.x;
        int kt = task >> 6, l = task & 63;
        int row = g * 512 + j * 16 + (l & 15);
        int k0  = kt * 32 + ((l >> 4) & 3) * 8;
        const float* s = src + (size_t)row * HID + k0;
        bf16x8 vh, vl;
        #pragma unroll
        for (int e = 0; e < 8; ++e){
            float v = s[e];
            unsigned short hb = f2bf(v);
            vh[e] = (short)hb;
            vl[e] = (short)f2bf(v - bf2f(hb));
        }
        size_t o = ((size_t)(jg * 16 + kt) * 64 + l) * 8;
        *(bf16x8*)(dh + o) = vh;
        *(bf16x8*)(dl + o) = vl;
    }
}

__global__ void __launch_bounds__(NTHR, 2)
lstm2_mfma(const float* __restrict__ x,
           const float* __restrict__ Wih0,
           const float* __restrict__ bih0, const float* __restrict__ bhh0,
           const float* __restrict__ bih1, const float* __restrict__ bhh1,
           const float* __restrict__ Wfc,  const float* __restrict__ bfc,
           float* __restrict__ out, char* __restrict__ ws)
{
    __shared__ float g1[4096];   // [2 kh][8 gn-tiles][16 q][16 b] = 16KB
    __shared__ float g2[4096];   // 16KB
    __shared__ float fcb[1536];  // 6KB

    const short* Wp = (const short*)ws;
    short* h1h_ws = (short*)(ws + H_OFF);
    short* h1l_ws = h1h_ws + HARR_E;
    short* h2h_ws = h1h_ws + 2 * HARR_E;
    short* h2l_ws = h1h_ws + 3 * HARR_E;
    float*  part  = (float*)(ws + PART_OFF);
    uint32* flags = (uint32*)(ws + FLAG_OFF);

    const int tid = threadIdx.x;
    const int wg  = blockIdx.x;
    const int grp = wg >> 5;          // wg&7==j&7 -> weight slices co-locate per XCD
    const int j   = wg & 31;

    // MFMA mapping (r3-proven): 8 waves = 4 gates x 2 k-halves; each wave both n, K=256
    const int wv = tid >> 6, lane = tid & 63;
    const int g  = wv >> 1, kh = wv & 1;
    const int ablk = (j * 4 + g) * 16;

    // pointwise mapping: 16 q x 32 b
    const int q  = tid >> 5, b = tid & 31;
    const int qg = j * 16 + q;
    const int nn = b >> 4, bl = b & 15;
    const int eidx = (((qg >> 5) * 2 + nn) * 64 + ((qg >> 3) & 3) * 16 + bl) * 8 + (qg & 7);

    float bias1[4], bias2[4], wxr[4][3];
    #pragma unroll
    for (int gg = 0; gg < 4; ++gg){
        int row = gg * 512 + qg;
        bias1[gg] = bih0[row] + bhh0[row];
        bias2[gg] = bih1[row] + bhh1[row];
        wxr[gg][0] = Wih0[row * 3 + 0];
        wxr[gg][1] = Wih0[row * 3 + 1];
        wxr[gg][2] = Wih0[row * 3 + 2];
    }
    const float wf0 = Wfc[qg], wf1 = Wfc[512 + qg], wf2 = Wfc[1024 + qg];
    const int   didx = j * 3 + (tid < 3 ? tid : 0);   // deferred-FC output row (d*32+bb)
    const float bfcv = bfc[didx >> 5];

    float c1 = 0.f, c2 = 0.f;

    // phase p: L1 computes t=p (p<512); L2 computes t=p-1 (p>=1).
    for (int p = 0; p <= SEQT; ++p){
        // ---- A: flag barrier (all 32 WGs of my group finished phase p-1) ----
        if (p > 0 && tid < 64){
            const uint32 need = (uint32)(p + 1);
            const uint32* f = flags + grp * SLICES * FLAG_STRIDE + tid * FLAG_STRIDE;
            while (true){
                uint32 v = (tid < SLICES)
                    ? __hip_atomic_load(f, __ATOMIC_RELAXED, __HIP_MEMORY_SCOPE_AGENT)
                    : 0xffffffffu;
                if (__all(v >= need)) break;
            }
        }
        __builtin_amdgcn_fence(__ATOMIC_ACQUIRE, "agent");
        __syncthreads();

        // ---- deferred FC for t=p-2 (3 threads; overlaps MFMA issue) ----
        if (p >= 2 && tid < 3){
            const float4* pr = (const float4*)(part +
                (((size_t)grp * 2 + ((p + 1) & 1)) * 96 + didx) * 32);
            float s = 0.f;
            #pragma unroll
            for (int c = 0; c < 8; ++c){ float4 t4 = pr[c]; s += t4.x + t4.y + t4.z + t4.w; }
            int dd = didx >> 5, bb = didx & 31;
            __hip_atomic_store(out + ((size_t)(grp * GB + bb) * SEQT + (p - 2)) * 3 + dd,
                               s + bfcv, __ATOMIC_RELAXED, __HIP_MEMORY_SCOPE_AGENT);
        }

        // ---- C: MFMA; A from L2-resident weights, B direct from global (post-fence) ----
        const short* b1hb = h1h_ws + (((p + 1) & 1) * GRPS + grp) * HBUF_E;
        const short* b1lb = h1l_ws + (((p + 1) & 1) * GRPS + grp) * HBUF_E;
        const short* b2hb = h2h_ws + ((p & 1) * GRPS + grp) * HBUF_E;
        const short* b2lb = h2l_ws + ((p & 1) * GRPS + grp) * HBUF_E;

        f32x4 acc1[2] = {{0.f,0.f,0.f,0.f},{0.f,0.f,0.f,0.f}};
        f32x4 acc2[2] = {{0.f,0.f,0.f,0.f},{0.f,0.f,0.f,0.f}};
        #pragma unroll 2
        for (int ks = 0; ks < 8; ++ks){
            const int kt = kh * 8 + ks;
            const size_t ao = ((size_t)(ablk + kt) * 64 + lane) * 8;
            bf16x8 a0h = *(const bf16x8*)(Wp + HI_BASE + ao);
            bf16x8 a1h = *(const bf16x8*)(Wp + HI_BASE + WM + ao);
            bf16x8 a2h = *(const bf16x8*)(Wp + HI_BASE + 2 * WM + ao);
            bf16x8 a0l = *(const bf16x8*)(Wp + ao);
            bf16x8 a1l = *(const bf16x8*)(Wp + WM + ao);
            bf16x8 a2l = *(const bf16x8*)(Wp + 2 * WM + ao);
            #pragma unroll
            for (int n = 0; n < 2; ++n){
                const int bo = ((kt * 2 + n) * 64 + lane) * 8;
                bf16x8 b1h = *(const bf16x8*)(b1hb + bo);
                bf16x8 b1l = *(const bf16x8*)(b1lb + bo);
                bf16x8 b2h = *(const bf16x8*)(b2hb + bo);
                bf16x8 b2l = *(const bf16x8*)(b2lb + bo);
                acc1[n] = __builtin_amdgcn_mfma_f32_16x16x32_bf16(a0h, b1h, acc1[n], 0, 0, 0);
                acc1[n] = __builtin_amdgcn_mfma_f32_16x16x32_bf16(a0h, b1l, acc1[n], 0, 0, 0);
                acc1[n] = __builtin_amdgcn_mfma_f32_16x16x32_bf16(a0l, b1h, acc1[n], 0, 0, 0);
                acc2[n] = __builtin_amdgcn_mfma_f32_16x16x32_bf16(a1h, b1h, acc2[n], 0, 0, 0);
                acc2[n] = __builtin_amdgcn_mfma_f32_16x16x32_bf16(a1h, b1l, acc2[n], 0, 0, 0);
                acc2[n] = __builtin_amdgcn_mfma_f32_16x16x32_bf16(a1l, b1h, acc2[n], 0, 0, 0);
                acc2[n] = __builtin_amdgcn_mfma_f32_16x16x32_bf16(a2h, b2h, acc2[n], 0, 0, 0);
                acc2[n] = __builtin_amdgcn_mfma_f32_16x16x32_bf16(a2h, b2l, acc2[n], 0, 0, 0);
                acc2[n] = __builtin_amdgcn_mfma_f32_16x16x32_bf16(a2l, b2h, acc2[n], 0, 0, 0);
            }
        }

        // ---- D: write kh-halves to DISJOINT LDS (pointwise adds both); ONE sync ----
        #pragma unroll
        for (int n = 0; n < 2; ++n){
            const int base = (kh * 8 + g * 2 + n) * 256 + (lane & 15);
            #pragma unroll
            for (int r = 0; r < 4; ++r){
                int row = (lane >> 4) * 4 + r;
                g1[base + row * 16] = acc1[n][r];
                g2[base + row * 16] = acc2[n][r];
            }
        }
        __syncthreads();

        // ---- E: pointwise L1 (t=p) ----
        if (p < SEQT){
            const int o0 = (0 * 2 + nn) * 256 + q * 16 + bl;
            const int o1 = (1 * 2 + nn) * 256 + q * 16 + bl;
            const int o2 = (2 * 2 + nn) * 256 + q * 16 + bl;
            const int o3 = (3 * 2 + nn) * 256 + q * 16 + bl;
            float gt0 = bias1[0] + g1[o0] + g1[2048 + o0];
            float gt1 = bias1[1] + g1[o1] + g1[2048 + o1];
            float gt2 = bias1[2] + g1[o2] + g1[2048 + o2];
            float gt3 = bias1[3] + g1[o3] + g1[2048 + o3];
            const float* xp = x + ((size_t)(grp * GB + b) * SEQT + p) * 3;
            float x0 = xp[0], x1 = xp[1], x2 = xp[2];
            gt0 += wxr[0][0] * x0 + wxr[0][1] * x1 + wxr[0][2] * x2;
            gt1 += wxr[1][0] * x0 + wxr[1][1] * x1 + wxr[1][2] * x2;
            gt2 += wxr[2][0] * x0 + wxr[2][1] * x1 + wxr[2][2] * x2;
            gt3 += wxr[3][0] * x0 + wxr[3][1] * x1 + wxr[3][2] * x2;
            float ii = sigm(gt0), ff = sigm(gt1), gv = tanh_(gt2), oo = sigm(gt3);
            c1 = ff * c1 + ii * gv;
            float h = oo * tanh_(c1);
            unsigned short hb = f2bf(h);
            unsigned short lb = f2bf(h - bf2f(hb));
            int base = ((p & 1) * GRPS + grp) * HBUF_E + eidx;
            __hip_atomic_store(h1h_ws + base, (short)hb, __ATOMIC_RELAXED, __HIP_MEMORY_SCOPE_AGENT);
            __hip_atomic_store(h1l_ws + base, (short)lb, __ATOMIC_RELAXED, __HIP_MEMORY_SCOPE_AGENT);
        }

        // ---- F: pointwise L2 (t=p-1) + FC partial staging ----
        if (p >= 1){
            const int o0 = (0 * 2 + nn) * 256 + q * 16 + bl;
            const int o1 = (1 * 2 + nn) * 256 + q * 16 + bl;
            const int o2 = (2 * 2 + nn) * 256 + q * 16 + bl;
            const int o3 = (3 * 2 + nn) * 256 + q * 16 + bl;
            float gt0 = bias2[0] + g2[o0] + g2[2048 + o0];
            float gt1 = bias2[1] + g2[o1] + g2[2048 + o1];
            float gt2 = bias2[2] + g2[o2] + g2[2048 + o2];
            float gt3 = bias2[3] + g2[o3] + g2[2048 + o3];
            float ii = sigm(gt0), ff = sigm(gt1), gv = tanh_(gt2), oo = sigm(gt3);
            c2 = ff * c2 + ii * gv;
            float h = oo * tanh_(c2);
            unsigned short hb = f2bf(h);
            unsigned short lb = f2bf(h - bf2f(hb));
            int base = (((p - 1) & 1) * GRPS + grp) * HBUF_E + eidx;
            __hip_atomic_store(h2h_ws + base, (short)hb, __ATOMIC_RELAXED, __HIP_MEMORY_SCOPE_AGENT);
            __hip_atomic_store(h2l_ws + base, (short)lb, __ATOMIC_RELAXED, __HIP_MEMORY_SCOPE_AGENT);
            fcb[0 * 512 + tid] = wf0 * h;
            fcb[1 * 512 + tid] = wf1 * h;
            fcb[2 * 512 + tid] = wf2 * h;
        }
        __syncthreads();

        // ---- G: FC per-slice partial ----
        if (p >= 1 && tid < 96){
            int d = tid >> 5;
            float s = 0.f;
            #pragma unroll
            for (int qq = 0; qq < 16; ++qq) s += fcb[d * 512 + qq * 32 + (tid & 31)];
            __hip_atomic_store(part + (((size_t)grp * 2 + (p & 1)) * 96 + tid) * 32 + j, s,
                               __ATOMIC_RELAXED, __HIP_MEMORY_SCOPE_AGENT);
        }
        __syncthreads();   // each wave drains vmcnt(0) at its barrier -> stores visible

        // ---- H: arrival ----
        if (tid == 0)
            __hip_atomic_store(flags + wg * FLAG_STRIDE, (uint32)(p + 2),
                               __ATOMIC_RELEASE, __HIP_MEMORY_SCOPE_AGENT);
    }

    // ---- drain: FC for t = SEQT-1 (partials written at phase SEQT) ----
    if (tid < 64){
        const uint32 need = (uint32)(SEQT + 2);
        const uint32* f = flags + grp * SLICES * FLAG_STRIDE + tid * FLAG_STRIDE;
        while (true){
            uint32 v = (tid < SLICES)
                ? __hip_atomic_load(f, __ATOMIC_RELAXED, __HIP_MEMORY_SCOPE_AGENT)
                : 0xffffffffu;
            if (__all(v >= need)) break;
        }
    }
    __builtin_amdgcn_fence(__ATOMIC_ACQUIRE, "agent");
    __syncthreads();
    if (tid < 3){
        const float4* pr = (const float4*)(part +
            (((size_t)grp * 2 + (SEQT & 1)) * 96 + didx) * 32);
        float s = 0.f;
        #pragma unroll
        for (int c = 0; c < 8; ++c){ float4 t4 = pr[c]; s += t4.x + t4.y + t4.z + t4.w; }
        int dd = didx >> 5, bb = didx & 31;
        __hip_atomic_store(out + ((size_t)(grp * GB + bb) * SEQT + (SEQT - 1)) * 3 + dd,
                           s + bfcv, __ATOMIC_RELAXED, __HIP_MEMORY_SCOPE_AGENT);
    }
}

extern "C" void kernel_launch(void* const* d_in, const int* in_sizes, int n_in,
                              void* d_out, int out_size, void* d_ws, size_t ws_size,
                              hipStream_t stream)
{
    (void)in_sizes; (void)n_in; (void)ws_size; (void)out_size;

    const float* x    = (const float*)d_in[0];
    const float* Wih0 = (const float*)d_in[1];
    const float* Whh0 = (const float*)d_in[2];
    const float* bih0 = (const float*)d_in[3];
    const float* bhh0 = (const float*)d_in[4];
    const float* Wih1 = (const float*)d_in[5];
    const float* Whh1 = (const float*)d_in[6];
    const float* bih1 = (const float*)d_in[7];
    const float* bhh1 = (const float*)d_in[8];
    const float* Wfc  = (const float*)d_in[9];
    const float* bfc  = (const float*)d_in[10];
    float* out = (float*)d_out;
    char*  ws  = (char*)d_ws;

    // zero h exchange (edge phases read zeros) and flags
    hipMemsetAsync(ws + H_OFF, 0, 4 * HARR_E * sizeof(short), stream);
    hipMemsetAsync(ws + FLAG_OFF, 0, FLAG_BYTES, stream);

    // pack weights (re-done every launch; d_ws is re-poisoned by the harness)
    prep_weights<<<dim3(128, 3), NTHR, 0, stream>>>(Whh0, Wih1, Whh1, (short*)ws);

    void* args[] = { (void*)&x, (void*)&Wih0, (void*)&bih0, (void*)&bhh0,
                     (void*)&bih1, (void*)&bhh1, (void*)&Wfc, (void*)&bfc,
                     (void*)&out, (void*)&ws };
    hipLaunchCooperativeKernel((const void*)lstm2_mfma, dim3(GRPS * SLICES), dim3(NTHR),
                               args, 0, stream);
}